// Round 4
// baseline (24072.398 us; speedup 1.0000x reference)
//
#include <hip/hip_runtime.h>
#include <cstdint>
#include <cstddef>

// Problem constants
#define TT   64
#define BB   32
#define CINC 64
#define HIDN 128
#define LL   256
#define LPP  128
#define NSAMP (TT*BB)   // 2048
#define LN_EPS 1e-5f

// ---------- small helpers ----------
__device__ __forceinline__ float bf2f(unsigned short u){
    union { unsigned int i; float f; } v; v.i = ((unsigned int)u) << 16; return v.f;
}
__device__ __forceinline__ unsigned short f2bf(float f){
    union { float f; unsigned int i; } v; v.f = f;
    unsigned int u = v.i;
    u = (u + 0x7FFFu + ((u >> 16) & 1u)) >> 16;   // RTNE
    return (unsigned short)u;
}
__device__ __forceinline__ float sigmoidf_(float x){ return 1.f/(1.f + __expf(-x)); }
__device__ __forceinline__ float tanhf_(float x){ return 1.f - 2.f/(__expf(2.f*x) + 1.f); }

// =====================================================================
// Phase 1: conv1d(x) + LN + maxpool -> bf16 xg.
// Weights staged per c-tile into LDS [8c][3k][128o] (12 KB), read as
// wave-uniform ds_read_b128 broadcasts: 12 LDS reads + 192 FMA per c per
// wave (16 rows). x window read vectorized (float4 + 2 scalars).
// Grid = NSAMP*4 (gate fastest -> 4 consecutive blocks share x[s] in L2).
// =====================================================================
__global__ __launch_bounds__(512, 4) void phase1_kernel(
    const float* __restrict__ x,
    const float* __restrict__ wx0, const float* __restrict__ bx0,
    const float* __restrict__ wx1, const float* __restrict__ bx1,
    const float* __restrict__ wx2, const float* __restrict__ bx2,
    const float* __restrict__ wx3, const float* __restrict__ bx3,
    const float* __restrict__ lnw, const float* __restrict__ lnb,
    unsigned int* __restrict__ xg)     // [4][NSAMP][HID][LP/2] dwords (2x bf16)
{
    const int bid = blockIdx.x;
    const int s = bid >> 2;            // sample
    const int g = bid & 3;             // gate

    const float* W; const float* Bv;
    if (g == 0)      { W = wx0; Bv = bx0; }
    else if (g == 1) { W = wx1; Bv = bx1; }
    else if (g == 2) { W = wx2; Bv = bx2; }
    else             { W = wx3; Bv = bx3; }

    const int tid  = threadIdx.x;
    const int lane = tid & 63;
    const int wv    = __builtin_amdgcn_readfirstlane(tid >> 6);  // 0..7
    const int obase = wv * 16;

    __shared__ float wt[8 * 3 * 128];   // [cl][k][o] = 12 KB
    __shared__ float red[16];

    const float* xs = x + (size_t)s * (CINC * LL);
    const int l0 = lane * 4;

    float acc[16][4];
    #pragma unroll
    for (int r = 0; r < 16; r++){ acc[r][0]=0.f; acc[r][1]=0.f; acc[r][2]=0.f; acc[r][3]=0.f; }

    const int o_st = tid >> 2;     // 0..127: output row this thread stages
    const int t4   = tid & 3;      // 4 threads per row, 6 floats each

    for (int ct = 0; ct < 8; ++ct){          // c-tiles of 8
        if (ct) __syncthreads();             // finish reads of previous tile
        // stage W[o][ct*8..ct*8+7][k] -> wt[cl][k][o]
        {
            const float* src = W + (size_t)o_st * 192 + ct * 24 + t4 * 6;
            const float2 s0 = *(const float2*)(src);
            const float2 s1 = *(const float2*)(src + 2);
            const float2 s2 = *(const float2*)(src + 4);
            const float vals[6] = { s0.x, s0.y, s1.x, s1.y, s2.x, s2.y };
            #pragma unroll
            for (int j = 0; j < 6; ++j){
                const int col = t4 * 6 + j;          // 0..23 within the tile
                const int cl  = col / 3;
                const int k   = col - cl * 3;
                wt[cl * 384 + k * 128 + o_st] = vals[j];
            }
        }
        __syncthreads();

        #pragma unroll
        for (int cl = 0; cl < 8; ++cl){
            const int c = ct * 8 + cl;
            const float* xr = xs + c * LL;
            float xv[6];
            const float4 xm = *(const float4*)(xr + l0);
            xv[1] = xm.x; xv[2] = xm.y; xv[3] = xm.z; xv[4] = xm.w;
            xv[0] = (l0 > 0)        ? xr[l0 - 1] : 0.f;
            xv[5] = (l0 + 4 < LL)   ? xr[l0 + 4] : 0.f;
            #pragma unroll
            for (int k = 0; k < 3; ++k){
                const float4* wrow = (const float4*)(wt + cl * 384 + k * 128 + obase);
                #pragma unroll
                for (int r4 = 0; r4 < 4; ++r4){
                    const float4 w4 = wrow[r4];       // 4 rows' weight at (c,k), broadcast
                    #pragma unroll
                    for (int q = 0; q < 4; ++q){
                        acc[r4*4+0][q] += w4.x * xv[q + k];
                        acc[r4*4+1][q] += w4.y * xv[q + k];
                        acc[r4*4+2][q] += w4.z * xv[q + k];
                        acc[r4*4+3][q] += w4.w * xv[q + k];
                    }
                }
            }
        }
    }

    float sum = 0.f, ssq = 0.f;
    #pragma unroll
    for (int r = 0; r < 16; r++){
        const float bo = Bv[obase + r];
        #pragma unroll
        for (int q = 0; q < 4; q++){
            float v = acc[r][q] + bo;
            acc[r][q] = v;
            sum += v; ssq += v * v;
        }
    }

    #pragma unroll
    for (int off = 32; off > 0; off >>= 1){
        sum += __shfl_down(sum, off, 64);
        ssq += __shfl_down(ssq, off, 64);
    }
    if (lane == 0){ red[wv] = sum; red[8 + wv] = ssq; }
    __syncthreads();
    float ts = 0.f, tq = 0.f;
    #pragma unroll
    for (int w = 0; w < 8; w++){ ts += red[w]; tq += red[8 + w]; }
    const float mu  = ts * (1.f / 32768.f);
    const float var = tq * (1.f / 32768.f) - mu * mu;
    const float inv = rsqrtf(var + LN_EPS);

    unsigned int* outb = xg + ((size_t)g * NSAMP + s) * (HIDN * (LPP/2));
    #pragma unroll
    for (int r = 0; r < 16; r++){
        const int o = obase + r;
        const float4 lw = *(const float4*)(lnw + (size_t)o * LL + l0);
        const float4 lb = *(const float4*)(lnb + (size_t)o * LL + l0);
        const float v0 = (acc[r][0] - mu) * inv * lw.x + lb.x;
        const float v1 = (acc[r][1] - mu) * inv * lw.y + lb.y;
        const float v2 = (acc[r][2] - mu) * inv * lw.z + lb.z;
        const float v3 = (acc[r][3] - mu) * inv * lw.w + lb.w;
        const float p0 = fmaxf(v0, v1);
        const float p1 = fmaxf(v2, v3);
        const unsigned int pk = (unsigned int)f2bf(p0) | ((unsigned int)f2bf(p1) << 16);
        outb[(size_t)o * (LPP/2) + lane] = pk;
    }
}

// =====================================================================
// One-time weight transpose: wh[g][hid][c3k] -> wT[hq][c3k][g][h]
// (hq = hid/2, h = hid&1). This is EXACTLY the per-block LDS image, so
// the per-step kernel stages it with a linear float4 copy.
// =====================================================================
__global__ void transpose_wh_kernel(
    const float* __restrict__ wh0, const float* __restrict__ wh1,
    const float* __restrict__ wh2, const float* __restrict__ wh3,
    float* __restrict__ wT)
{
    const int hq  = blockIdx.x;          // 0..63
    const int tid = threadIdx.x;         // 0..255
    for (int j = tid; j < 3072; j += 256){
        const int c3k = j >> 3;
        const int g   = (j >> 1) & 3;
        const int h   = j & 1;
        const float* Wg = (g == 0) ? wh0 : (g == 1) ? wh1 : (g == 2) ? wh2 : wh3;
        wT[(size_t)hq * 3072 + j] = Wg[(size_t)(hq * 2 + h) * 384 + c3k];
    }
}

// =====================================================================
// Phase 2 (per step): block owns (b, 2 hid), grid (32,64) = 2048 blocks,
// 128 thr (= l), 12 KB LDS, __launch_bounds__(128,4) -> 8 blocks/CU =
// 4 waves/SIMD. Staging = linear float4 copy of pre-transposed weights.
// Per c: 3 VMEM h-loads (prefetched) + 6 broadcast ds_read_b128 + 24 FMA.
// =====================================================================
__global__ __launch_bounds__(128, 4) void phase2_kernel(
    const float* __restrict__ hprev,          // [B][HID][LP]
    const unsigned short* __restrict__ xg,    // [4][NSAMP][HID][LP] bf16
    const float* __restrict__ wT,             // [64][384][4][2]
    const float* __restrict__ bh0, const float* __restrict__ bh1,
    const float* __restrict__ bh2, const float* __restrict__ bh3,
    float* __restrict__ hout,                 // d_out + t*B*HID*LP
    float* __restrict__ cst,                  // [B][HID][LP]
    int t, int first)
{
    const int b   = blockIdx.x;
    const int hq  = blockIdx.y;      // hid pair 0..63
    const int l   = threadIdx.x;     // 0..127
    const int hid0 = hq * 2;

    __shared__ float wlds[384 * 8];  // [c3k][g][h] = 12 KB

    float acc[4][2];
    #pragma unroll
    for (int g = 0; g < 4; ++g){ acc[g][0] = 0.f; acc[g][1] = 0.f; }

    if (!first){
        const float4* src = (const float4*)(wT + (size_t)hq * 3072);
        float4* dst = (float4*)wlds;
        #pragma unroll
        for (int i = 0; i < 6; ++i) dst[l + 128 * i] = src[l + 128 * i];
        __syncthreads();

        const float* hb = hprev + (size_t)b * (HIDN * LPP);
        const float4* wl4 = (const float4*)wlds;

        float nv0 = (l > 0)       ? hb[l - 1] : 0.f;
        float nv1 =                 hb[l];
        float nv2 = (l < LPP - 1) ? hb[l + 1] : 0.f;

        #pragma unroll 2
        for (int c = 0; c < HIDN; ++c){
            const float hv0 = nv0, hv1 = nv1, hv2 = nv2;
            const float* hr = hb + (size_t)((c + 1 < HIDN) ? c + 1 : c) * LPP;
            nv0 = (l > 0)       ? hr[l - 1] : 0.f;
            nv1 =                 hr[l];
            nv2 = (l < LPP - 1) ? hr[l + 1] : 0.f;

            #pragma unroll
            for (int k = 0; k < 3; ++k){
                const float hk = (k == 0) ? hv0 : (k == 1) ? hv1 : hv2;
                const int c3k = c * 3 + k;
                const float4 wa = wl4[c3k * 2];      // {g0h0,g0h1,g1h0,g1h1}
                const float4 wb = wl4[c3k * 2 + 1];  // {g2h0,g2h1,g3h0,g3h1}
                acc[0][0] += wa.x * hk; acc[0][1] += wa.y * hk;
                acc[1][0] += wa.z * hk; acc[1][1] += wa.w * hk;
                acc[2][0] += wb.x * hk; acc[2][1] += wb.y * hk;
                acc[3][0] += wb.z * hk; acc[3][1] += wb.w * hk;
            }
        }
    }

    const int sidx = t * BB + b;
    const float* bp[4] = { bh0, bh1, bh2, bh3 };
    float pre[4][2];
    #pragma unroll
    for (int g = 0; g < 4; ++g){
        #pragma unroll
        for (int h = 0; h < 2; ++h){
            const float xgv = bf2f(xg[(((size_t)g * NSAMP + sidx) * HIDN + hid0 + h) * LPP + l]);
            pre[g][h] = acc[g][h] + bp[g][hid0 + h] + xgv;
        }
    }

    #pragma unroll
    for (int h = 0; h < 2; ++h){
        const int hid = hid0 + h;
        float* cp = cst + ((size_t)b * HIDN + hid) * LPP + l;
        const float cv = first ? 0.f : *cp;
        const float ig = sigmoidf_(pre[0][h]);
        const float fg = sigmoidf_(pre[1][h]);
        const float gg = tanhf_(pre[2][h]);
        const float og = sigmoidf_(pre[3][h]);
        const float cn = fg * cv + ig * gg;
        *cp = cn;
        hout[((size_t)b * HIDN + hid) * LPP + l] = og * tanhf_(cn);
    }
}

// =====================================================================
// Host side
// =====================================================================
extern "C" void kernel_launch(void* const* d_in, const int* in_sizes, int n_in,
                              void* d_out, int out_size, void* d_ws, size_t ws_size,
                              hipStream_t stream)
{
    const float* x = (const float*)d_in[0];

    const float* wxp[4] = {nullptr,nullptr,nullptr,nullptr};
    const float* bxp[4] = {nullptr,nullptr,nullptr,nullptr};
    const float* whp[4] = {nullptr,nullptr,nullptr,nullptr};
    const float* bhp[4] = {nullptr,nullptr,nullptr,nullptr};
    const float* lnw = nullptr; const float* lnb = nullptr;
    int nwx = 0, nwh = 0, pend = -1;
    for (int i = 1; i < n_in; i++){
        const float* p = (const float*)d_in[i];
        const int sz = in_sizes[i];
        if (sz == HIDN * CINC * 3)      { wxp[nwx] = p; pend = 0; }
        else if (sz == HIDN * HIDN * 3) { whp[nwh] = p; pend = 1; }
        else if (sz == HIDN)            { if (pend == 0) bxp[nwx++] = p; else bhp[nwh++] = p; pend = -1; }
        else if (sz == HIDN * LL)       { if (!lnw) lnw = p; else lnb = p; }
    }

    // Workspace: xg (bf16, 256 MiB), wT (768 KiB), c-state (2 MiB).
    unsigned int*   xg_u32 = (unsigned int*)d_ws;
    unsigned short* xg_u16 = (unsigned short*)d_ws;
    const size_t xg_bytes = (size_t)4 * NSAMP * HIDN * LPP * 2;
    float* wT  = (float*)((char*)d_ws + xg_bytes);
    float* cst = (float*)((char*)d_ws + xg_bytes + (size_t)64 * 3072 * 4);
    float* out = (float*)d_out;

    phase1_kernel<<<dim3(NSAMP * 4), 512, 0, stream>>>(
        x, wxp[0], bxp[0], wxp[1], bxp[1], wxp[2], bxp[2], wxp[3], bxp[3],
        lnw, lnb, xg_u32);

    transpose_wh_kernel<<<dim3(64), 256, 0, stream>>>(
        whp[0], whp[1], whp[2], whp[3], wT);

    for (int t = 0; t < TT; t++){
        const float* hprev = (t == 0) ? out : out + (size_t)(t - 1) * BB * HIDN * LPP;
        phase2_kernel<<<dim3(BB, 64), 128, 0, stream>>>(
            hprev, xg_u16, wT,
            bhp[0], bhp[1], bhp[2], bhp[3],
            out + (size_t)t * BB * HIDN * LPP, cst, t, (t == 0) ? 1 : 0);
    }
}

// Round 5
// 15442.697 us; speedup vs baseline: 1.5588x; 1.5588x over previous
//
#include <hip/hip_runtime.h>
#include <cstdint>
#include <cstddef>

// Problem constants
#define TT   64
#define BB   32
#define CINC 64
#define HIDN 128
#define LL   256
#define LPP  128
#define NSAMP (TT*BB)   // 2048
#define LN_EPS 1e-5f

// ---------- small helpers ----------
__device__ __forceinline__ float bf2f(unsigned short u){
    union { unsigned int i; float f; } v; v.i = ((unsigned int)u) << 16; return v.f;
}
__device__ __forceinline__ unsigned short f2bf(float f){
    union { float f; unsigned int i; } v; v.f = f;
    unsigned int u = v.i;
    u = (u + 0x7FFFu + ((u >> 16) & 1u)) >> 16;   // RTNE
    return (unsigned short)u;
}
__device__ __forceinline__ float sigmoidf_(float x){ return 1.f/(1.f + __expf(-x)); }
__device__ __forceinline__ float tanhf_(float x){ return 1.f - 2.f/(__expf(2.f*x) + 1.f); }

// =====================================================================
// Phase 1: conv1d(x) + LN + maxpool -> bf16 xg.
// LDS weight tiles [8c][3k][o] read as wave-uniform ds_read_b128
// broadcasts. R5 fixes vs R4: (a) __launch_bounds__(512,2) -- the (512,4)
// budget of 128 regs/wave spilled acc[16][4] to scratch (74 GB HBM
// traffic, 21 ms); (b) k-row stride padded 128->132 floats so the
// transposing staging writes are 2-way-bank max (was 4-way, 1.9e7
// conflicts).
// =====================================================================
__global__ __launch_bounds__(512, 2) void phase1_kernel(
    const float* __restrict__ x,
    const float* __restrict__ wx0, const float* __restrict__ bx0,
    const float* __restrict__ wx1, const float* __restrict__ bx1,
    const float* __restrict__ wx2, const float* __restrict__ bx2,
    const float* __restrict__ wx3, const float* __restrict__ bx3,
    const float* __restrict__ lnw, const float* __restrict__ lnb,
    unsigned int* __restrict__ xg)     // [4][NSAMP][HID][LP/2] dwords (2x bf16)
{
    const int bid = blockIdx.x;
    const int s = bid >> 2;            // sample
    const int g = bid & 3;             // gate

    const float* W; const float* Bv;
    if (g == 0)      { W = wx0; Bv = bx0; }
    else if (g == 1) { W = wx1; Bv = bx1; }
    else if (g == 2) { W = wx2; Bv = bx2; }
    else             { W = wx3; Bv = bx3; }

    const int tid  = threadIdx.x;
    const int lane = tid & 63;
    const int wv    = __builtin_amdgcn_readfirstlane(tid >> 6);  // 0..7
    const int obase = wv * 16;

    // padded strides: k-row = 132 floats, cl = 396 floats (12.7 KB)
    __shared__ float wt[8 * 396];
    __shared__ float red[16];

    const float* xs = x + (size_t)s * (CINC * LL);
    const int l0 = lane * 4;

    float acc[16][4];
    #pragma unroll
    for (int r = 0; r < 16; r++){ acc[r][0]=0.f; acc[r][1]=0.f; acc[r][2]=0.f; acc[r][3]=0.f; }

    const int o_st = tid >> 2;     // 0..127: output row this thread stages
    const int t4   = tid & 3;      // 4 threads per row, 6 floats each

    for (int ct = 0; ct < 8; ++ct){          // c-tiles of 8
        if (ct) __syncthreads();             // finish reads of previous tile
        // stage W[o][ct*8..ct*8+7][k] -> wt[cl][k][o]
        {
            const float* src = W + (size_t)o_st * 192 + ct * 24 + t4 * 6;
            const float2 s0 = *(const float2*)(src);
            const float2 s1 = *(const float2*)(src + 2);
            const float2 s2 = *(const float2*)(src + 4);
            const float vals[6] = { s0.x, s0.y, s1.x, s1.y, s2.x, s2.y };
            #pragma unroll
            for (int j = 0; j < 6; ++j){
                const int col = t4 * 6 + j;          // 0..23 within the tile
                const int cl  = col / 3;
                const int k   = col - cl * 3;
                wt[cl * 396 + k * 132 + o_st] = vals[j];
            }
        }
        __syncthreads();

        #pragma unroll
        for (int cl = 0; cl < 8; ++cl){
            const int c = ct * 8 + cl;
            const float* xr = xs + c * LL;
            float xv[6];
            const float4 xm = *(const float4*)(xr + l0);
            xv[1] = xm.x; xv[2] = xm.y; xv[3] = xm.z; xv[4] = xm.w;
            xv[0] = (l0 > 0)        ? xr[l0 - 1] : 0.f;
            xv[5] = (l0 + 4 < LL)   ? xr[l0 + 4] : 0.f;
            #pragma unroll
            for (int k = 0; k < 3; ++k){
                const float4* wrow = (const float4*)(wt + cl * 396 + k * 132 + obase);
                #pragma unroll
                for (int r4 = 0; r4 < 4; ++r4){
                    const float4 w4 = wrow[r4];       // 4 rows' weight at (c,k), broadcast
                    #pragma unroll
                    for (int q = 0; q < 4; ++q){
                        acc[r4*4+0][q] += w4.x * xv[q + k];
                        acc[r4*4+1][q] += w4.y * xv[q + k];
                        acc[r4*4+2][q] += w4.z * xv[q + k];
                        acc[r4*4+3][q] += w4.w * xv[q + k];
                    }
                }
            }
        }
    }

    float sum = 0.f, ssq = 0.f;
    #pragma unroll
    for (int r = 0; r < 16; r++){
        const float bo = Bv[obase + r];
        #pragma unroll
        for (int q = 0; q < 4; q++){
            float v = acc[r][q] + bo;
            acc[r][q] = v;
            sum += v; ssq += v * v;
        }
    }

    #pragma unroll
    for (int off = 32; off > 0; off >>= 1){
        sum += __shfl_down(sum, off, 64);
        ssq += __shfl_down(ssq, off, 64);
    }
    if (lane == 0){ red[wv] = sum; red[8 + wv] = ssq; }
    __syncthreads();
    float ts = 0.f, tq = 0.f;
    #pragma unroll
    for (int w = 0; w < 8; w++){ ts += red[w]; tq += red[8 + w]; }
    const float mu  = ts * (1.f / 32768.f);
    const float var = tq * (1.f / 32768.f) - mu * mu;
    const float inv = rsqrtf(var + LN_EPS);

    unsigned int* outb = xg + ((size_t)g * NSAMP + s) * (HIDN * (LPP/2));
    #pragma unroll
    for (int r = 0; r < 16; r++){
        const int o = obase + r;
        const float4 lw = *(const float4*)(lnw + (size_t)o * LL + l0);
        const float4 lb = *(const float4*)(lnb + (size_t)o * LL + l0);
        const float v0 = (acc[r][0] - mu) * inv * lw.x + lb.x;
        const float v1 = (acc[r][1] - mu) * inv * lw.y + lb.y;
        const float v2 = (acc[r][2] - mu) * inv * lw.z + lb.z;
        const float v3 = (acc[r][3] - mu) * inv * lw.w + lb.w;
        const float p0 = fmaxf(v0, v1);
        const float p1 = fmaxf(v2, v3);
        const unsigned int pk = (unsigned int)f2bf(p0) | ((unsigned int)f2bf(p1) << 16);
        outb[(size_t)o * (LPP/2) + lane] = pk;
    }
}

// =====================================================================
// One-time weight transpose: wh[g][hid][c3k] -> wT2[hq][c3k][h][g]
// (hq = hid/4, h = hid&3). Exactly the per-block LDS image of phase 2,
// so per-step staging is a linear float4 copy.
// =====================================================================
__global__ void transpose_wh_kernel(
    const float* __restrict__ wh0, const float* __restrict__ wh1,
    const float* __restrict__ wh2, const float* __restrict__ wh3,
    float* __restrict__ wT2)
{
    const int hq  = blockIdx.x;          // 0..31
    const int tid = threadIdx.x;         // 0..255
    for (int j = tid; j < 6144; j += 256){
        const int c3k = j >> 4;
        const int h   = (j >> 2) & 3;
        const int g   = j & 3;
        const float* Wg = (g == 0) ? wh0 : (g == 1) ? wh1 : (g == 2) ? wh2 : wh3;
        wT2[(size_t)hq * 6144 + j] = Wg[(size_t)(hq * 4 + h) * 384 + c3k];
    }
}

// =====================================================================
// Phase 2 (R5 redesign): 4 l per lane. Block owns (b, 4 hid); 128 thr =
// 32 l-quads x 4 hid (lq = tid&31, hp = tid>>5). LDS [c3k][h4][g4] f32 =
// 24 KB, staged by linear float4 copy of wT2. Per c3k one broadcast
// ds_read_b128 gives the lane's 4 gate weights -> 16 FMAs per read
// (4x better read amortization than 1-l-per-lane). Epilogue xg/cst/hout
// all vectorized (ushort4/float4).
// =====================================================================
__global__ __launch_bounds__(128, 4) void phase2_kernel(
    const float* __restrict__ hprev,          // [B][HID][LP]
    const unsigned short* __restrict__ xg,    // [4][NSAMP][HID][LP] bf16
    const float* __restrict__ wT2,            // [32][384][4][4]
    const float* __restrict__ bh0, const float* __restrict__ bh1,
    const float* __restrict__ bh2, const float* __restrict__ bh3,
    float* __restrict__ hout,                 // d_out + t*B*HID*LP
    float* __restrict__ cst,                  // [B][HID][LP]
    int t, int first)
{
    const int b   = blockIdx.x;      // 0..31
    const int hq  = blockIdx.y;      // 0..31 (4 hid each)
    const int tid = threadIdx.x;     // 0..127
    const int lq  = tid & 31;        // l-quad
    const int hp  = tid >> 5;        // 0..3
    const int l0  = lq * 4;
    const int hid = hq * 4 + hp;

    __shared__ float wlds[384 * 16]; // [c3k][h4][g4] = 24 KB

    float acc[4][4];                 // [g][j]  j = l offset 0..3
    #pragma unroll
    for (int g = 0; g < 4; g++){
        #pragma unroll
        for (int j = 0; j < 4; j++) acc[g][j] = 0.f;
    }

    if (!first){
        // stage weights: 6144 floats = 1536 float4, linear copy
        const float4* src = (const float4*)(wT2 + (size_t)hq * 6144);
        float4* dst = (float4*)wlds;
        #pragma unroll
        for (int i = 0; i < 12; ++i) dst[tid + 128 * i] = src[tid + 128 * i];
        __syncthreads();

        const float* hb = hprev + (size_t)b * (HIDN * LPP);
        const float4* wl4 = (const float4*)wlds;

        // window regs: win[0..5] = h[c][l0-1 .. l0+4]; prefetch c=0
        float4 nm = *(const float4*)(hb + l0);
        float ne0 = (l0 > 0)         ? hb[l0 - 1] : 0.f;
        float ne5 = (l0 + 4 < LPP)   ? hb[l0 + 4] : 0.f;

        #pragma unroll 2
        for (int c = 0; c < HIDN; ++c){
            float win[6];
            win[0] = ne0; win[1] = nm.x; win[2] = nm.y;
            win[3] = nm.z; win[4] = nm.w; win[5] = ne5;
            // prefetch next row
            const float* hr = hb + (size_t)((c + 1 < HIDN) ? c + 1 : c) * LPP;
            nm  = *(const float4*)(hr + l0);
            ne0 = (l0 > 0)       ? hr[l0 - 1] : 0.f;
            ne5 = (l0 + 4 < LPP) ? hr[l0 + 4] : 0.f;

            #pragma unroll
            for (int k = 0; k < 3; ++k){
                const float4 w = wl4[(c * 3 + k) * 4 + hp];  // g0..g3 for this hid
                #pragma unroll
                for (int j = 0; j < 4; ++j){
                    const float hk = win[j + k];
                    acc[0][j] += w.x * hk;
                    acc[1][j] += w.y * hk;
                    acc[2][j] += w.z * hk;
                    acc[3][j] += w.w * hk;
                }
            }
        }
    }

    const int sidx = t * BB + b;
    const float* bp[4] = { bh0, bh1, bh2, bh3 };
    float pre[4][4];
    #pragma unroll
    for (int g = 0; g < 4; ++g){
        const ushort4 xq = *(const ushort4*)(xg + (((size_t)g * NSAMP + sidx) * HIDN + hid) * LPP + l0);
        const float bias = bp[g][hid];
        pre[g][0] = acc[g][0] + bias + bf2f(xq.x);
        pre[g][1] = acc[g][1] + bias + bf2f(xq.y);
        pre[g][2] = acc[g][2] + bias + bf2f(xq.z);
        pre[g][3] = acc[g][3] + bias + bf2f(xq.w);
    }

    float* cp = cst + ((size_t)b * HIDN + hid) * LPP + l0;
    float4 cv = first ? make_float4(0.f, 0.f, 0.f, 0.f) : *(const float4*)cp;
    float4 cn, hn;
    {
        const float ig = sigmoidf_(pre[0][0]);
        const float fg = sigmoidf_(pre[1][0]);
        const float gg = tanhf_(pre[2][0]);
        const float og = sigmoidf_(pre[3][0]);
        cn.x = fg * cv.x + ig * gg; hn.x = og * tanhf_(cn.x);
    }
    {
        const float ig = sigmoidf_(pre[0][1]);
        const float fg = sigmoidf_(pre[1][1]);
        const float gg = tanhf_(pre[2][1]);
        const float og = sigmoidf_(pre[3][1]);
        cn.y = fg * cv.y + ig * gg; hn.y = og * tanhf_(cn.y);
    }
    {
        const float ig = sigmoidf_(pre[0][2]);
        const float fg = sigmoidf_(pre[1][2]);
        const float gg = tanhf_(pre[2][2]);
        const float og = sigmoidf_(pre[3][2]);
        cn.z = fg * cv.z + ig * gg; hn.z = og * tanhf_(cn.z);
    }
    {
        const float ig = sigmoidf_(pre[0][3]);
        const float fg = sigmoidf_(pre[1][3]);
        const float gg = tanhf_(pre[2][3]);
        const float og = sigmoidf_(pre[3][3]);
        cn.w = fg * cv.w + ig * gg; hn.w = og * tanhf_(cn.w);
    }
    *(float4*)cp = cn;
    *(float4*)(hout + ((size_t)b * HIDN + hid) * LPP + l0) = hn;
}

// =====================================================================
// Host side
// =====================================================================
extern "C" void kernel_launch(void* const* d_in, const int* in_sizes, int n_in,
                              void* d_out, int out_size, void* d_ws, size_t ws_size,
                              hipStream_t stream)
{
    const float* x = (const float*)d_in[0];

    const float* wxp[4] = {nullptr,nullptr,nullptr,nullptr};
    const float* bxp[4] = {nullptr,nullptr,nullptr,nullptr};
    const float* whp[4] = {nullptr,nullptr,nullptr,nullptr};
    const float* bhp[4] = {nullptr,nullptr,nullptr,nullptr};
    const float* lnw = nullptr; const float* lnb = nullptr;
    int nwx = 0, nwh = 0, pend = -1;
    for (int i = 1; i < n_in; i++){
        const float* p = (const float*)d_in[i];
        const int sz = in_sizes[i];
        if (sz == HIDN * CINC * 3)      { wxp[nwx] = p; pend = 0; }
        else if (sz == HIDN * HIDN * 3) { whp[nwh] = p; pend = 1; }
        else if (sz == HIDN)            { if (pend == 0) bxp[nwx++] = p; else bhp[nwh++] = p; pend = -1; }
        else if (sz == HIDN * LL)       { if (!lnw) lnw = p; else lnb = p; }
    }

    // Workspace: xg (bf16, 256 MiB), wT2 (768 KiB), c-state (2 MiB).
    unsigned int*   xg_u32 = (unsigned int*)d_ws;
    unsigned short* xg_u16 = (unsigned short*)d_ws;
    const size_t xg_bytes = (size_t)4 * NSAMP * HIDN * LPP * 2;
    float* wT2 = (float*)((char*)d_ws + xg_bytes);
    float* cst = (float*)((char*)d_ws + xg_bytes + (size_t)32 * 6144 * 4);
    float* out = (float*)d_out;

    phase1_kernel<<<dim3(NSAMP * 4), 512, 0, stream>>>(
        x, wxp[0], bxp[0], wxp[1], bxp[1], wxp[2], bxp[2], wxp[3], bxp[3],
        lnw, lnb, xg_u32);

    transpose_wh_kernel<<<dim3(32), 256, 0, stream>>>(
        whp[0], whp[1], whp[2], whp[3], wT2);

    for (int t = 0; t < TT; t++){
        const float* hprev = (t == 0) ? out : out + (size_t)(t - 1) * BB * HIDN * LPP;
        phase2_kernel<<<dim3(BB, 32), 128, 0, stream>>>(
            hprev, xg_u16, wT2,
            bhp[0], bhp[1], bhp[2], bhp[3],
            out + (size_t)t * BB * HIDN * LPP, cst, t, (t == 0) ? 1 : 0);
    }
}

// Round 6
// 13541.374 us; speedup vs baseline: 1.7777x; 1.1404x over previous
//
#include <hip/hip_runtime.h>
#include <cstdint>
#include <cstddef>

// Problem constants
#define TT   64
#define BB   32
#define CINC 64
#define HIDN 128
#define LL   256
#define LPP  128
#define NSAMP (TT*BB)   // 2048
#define LN_EPS 1e-5f

// ---------- small helpers ----------
__device__ __forceinline__ float bf2f(unsigned short u){
    union { unsigned int i; float f; } v; v.i = ((unsigned int)u) << 16; return v.f;
}
__device__ __forceinline__ unsigned short f2bf(float f){
    union { float f; unsigned int i; } v; v.f = f;
    unsigned int u = v.i;
    u = (u + 0x7FFFu + ((u >> 16) & 1u)) >> 16;   // RTNE
    return (unsigned short)u;
}
__device__ __forceinline__ float sigmoidf_(float x){ return 1.f/(1.f + __expf(-x)); }
__device__ __forceinline__ float tanhf_(float x){ return 1.f - 2.f/(__expf(2.f*x) + 1.f); }

// =====================================================================
// Phase 1: conv1d(x) + LN + maxpool -> bf16 xg.
// VERBATIM the R1-measured kernel: 1735 us, 48 VGPR, no spill,
// VALUBusy 72%. Direct global weight reads (compiler keeps acc in
// AGPRs). Both LDS-staged variants (R4/R5) spilled acc to scratch
// (42-74 GB HBM traffic) -- do not restructure this kernel blind.
// =====================================================================
__global__ __launch_bounds__(512, 2) void phase1_kernel(
    const float* __restrict__ x,
    const float* __restrict__ wx0, const float* __restrict__ bx0,
    const float* __restrict__ wx1, const float* __restrict__ bx1,
    const float* __restrict__ wx2, const float* __restrict__ bx2,
    const float* __restrict__ wx3, const float* __restrict__ bx3,
    const float* __restrict__ lnw, const float* __restrict__ lnb,
    unsigned int* __restrict__ xg)     // [4][NSAMP][HID][LP/2] dwords (2x bf16)
{
    const int s = blockIdx.x;          // sample (t*B+b)
    const int g = blockIdx.y;          // gate

    const float* W; const float* Bv;
    if (g == 0)      { W = wx0; Bv = bx0; }
    else if (g == 1) { W = wx1; Bv = bx1; }
    else if (g == 2) { W = wx2; Bv = bx2; }
    else             { W = wx3; Bv = bx3; }

    const int tid  = threadIdx.x;
    const int lane = tid & 63;
    const int wv    = __builtin_amdgcn_readfirstlane(tid >> 6);  // 0..7
    const int obase = wv * 16;

    const float* xs = x + (size_t)s * (CINC * LL);
    const int l0 = lane * 4;

    float acc[16][4];
    #pragma unroll
    for (int r = 0; r < 16; r++){ acc[r][0]=0.f; acc[r][1]=0.f; acc[r][2]=0.f; acc[r][3]=0.f; }

    for (int c = 0; c < CINC; c++){
        const float* xr = xs + c * LL;
        float xv[6];
        #pragma unroll
        for (int d = 0; d < 6; d++){
            int l = l0 + d - 1;
            xv[d] = (l >= 0 && l < LL) ? xr[l] : 0.f;
        }
        const float* wc = W + (size_t)c * 3;
        #pragma unroll
        for (int r = 0; r < 16; r++){
            const int o = obase + r;
            const float* wo = wc + (size_t)o * (CINC * 3);
            const float w0 = wo[0], w1 = wo[1], w2 = wo[2];
            #pragma unroll
            for (int q = 0; q < 4; q++){
                acc[r][q] += w0 * xv[q] + w1 * xv[q+1] + w2 * xv[q+2];
            }
        }
    }

    float sum = 0.f, ssq = 0.f;
    #pragma unroll
    for (int r = 0; r < 16; r++){
        const float bo = Bv[obase + r];
        #pragma unroll
        for (int q = 0; q < 4; q++){
            float v = acc[r][q] + bo;
            acc[r][q] = v;
            sum += v; ssq += v * v;
        }
    }

    #pragma unroll
    for (int off = 32; off > 0; off >>= 1){
        sum += __shfl_down(sum, off, 64);
        ssq += __shfl_down(ssq, off, 64);
    }
    __shared__ float red[16];
    if (lane == 0){ red[wv] = sum; red[8 + wv] = ssq; }
    __syncthreads();
    float ts = 0.f, tq = 0.f;
    #pragma unroll
    for (int w = 0; w < 8; w++){ ts += red[w]; tq += red[8 + w]; }
    const float mu  = ts * (1.f / 32768.f);
    const float var = tq * (1.f / 32768.f) - mu * mu;
    const float inv = rsqrtf(var + LN_EPS);

    unsigned int* outb = xg + ((size_t)g * NSAMP + s) * (HIDN * (LPP/2));
    #pragma unroll
    for (int r = 0; r < 16; r++){
        const int o = obase + r;
        const float4 lw = *(const float4*)(lnw + (size_t)o * LL + l0);
        const float4 lb = *(const float4*)(lnb + (size_t)o * LL + l0);
        const float v0 = (acc[r][0] - mu) * inv * lw.x + lb.x;
        const float v1 = (acc[r][1] - mu) * inv * lw.y + lb.y;
        const float v2 = (acc[r][2] - mu) * inv * lw.z + lb.z;
        const float v3 = (acc[r][3] - mu) * inv * lw.w + lb.w;
        const float p0 = fmaxf(v0, v1);
        const float p1 = fmaxf(v2, v3);
        const unsigned int pk = (unsigned int)f2bf(p0) | ((unsigned int)f2bf(p1) << 16);
        outb[(size_t)o * (LPP/2) + lane] = pk;
    }
}

// =====================================================================
// One-time weight transpose: wh[g][hid][c3k] -> wT2[hq][c3k][h][g]
// (hq = hid/4, h = hid&3). Exactly the per-block LDS image of phase 2.
// =====================================================================
__global__ void transpose_wh_kernel(
    const float* __restrict__ wh0, const float* __restrict__ wh1,
    const float* __restrict__ wh2, const float* __restrict__ wh3,
    float* __restrict__ wT2)
{
    const int hq  = blockIdx.x;          // 0..31
    const int tid = threadIdx.x;         // 0..255
    for (int j = tid; j < 6144; j += 256){
        const int c3k = j >> 4;
        const int h   = (j >> 2) & 3;
        const int g   = j & 3;
        const float* Wg = (g == 0) ? wh0 : (g == 1) ? wh1 : (g == 2) ? wh2 : wh3;
        wT2[(size_t)hq * 6144 + j] = Wg[(size_t)(hq * 4 + h) * 384 + c3k];
    }
}

// =====================================================================
// Phase 2 (R6): ONE persistent kernel, plain launch, flag-based sync.
// Grid 1024 = 32 b x 32 hq, 128 thr (lq=tid&31 owns 4 l; hp=tid>>5 owns
// hid hq*4+hp). Exactly 4 blocks/CU co-resident (24KB LDS x4 = 96KB,
// __launch_bounds__(128,2) -> VGPR cap 256, 2 waves/SIMD). Weights in
// LDS once; c-state in registers; xg issued BEFORE the spin; h prefetch
// 2-deep. b = blockIdx&31 puts all consumers of h[b] on one XCD (L2
// locality); correctness relies on release/acquire agent atomics only.
// Per-step dispatch overhead (~30-40us x64 in R1/R4/R5) eliminated.
// =====================================================================
__global__ __launch_bounds__(128, 2) void phase2_persist(
    const unsigned short* __restrict__ xg,    // [4][NSAMP][HID][LP] bf16
    const float* __restrict__ wT2,            // [32][384][4][4]
    const float* __restrict__ bh0, const float* __restrict__ bh1,
    const float* __restrict__ bh2, const float* __restrict__ bh3,
    float* __restrict__ out,                  // [T][B][HID][LP]
    unsigned int* __restrict__ cnt)           // [TT] arrival counters (zeroed)
{
    const int b   = blockIdx.x & 31;
    const int hq  = blockIdx.x >> 5;     // 0..31
    const int tid = threadIdx.x;         // 0..127
    const int lq  = tid & 31;
    const int hp  = tid >> 5;            // 0..3
    const int l0  = lq * 4;
    const int hid = hq * 4 + hp;

    __shared__ float wlds[384 * 16];     // [c3k][h4][g4] = 24 KB

    // ---- stage weights once ----
    {
        const float4* src = (const float4*)(wT2 + (size_t)hq * 6144);
        float4* dst = (float4*)wlds;
        #pragma unroll
        for (int i = 0; i < 12; ++i) dst[tid + 128 * i] = src[tid + 128 * i];
    }
    const float bias0 = bh0[hid], bias1 = bh1[hid], bias2 = bh2[hid], bias3 = bh3[hid];
    __syncthreads();

    const float4* wl4 = (const float4*)wlds;
    float4 cv = make_float4(0.f, 0.f, 0.f, 0.f);

    for (int t = 0; t < TT; ++t){
        // xg loads: independent of h -> issue before the spin
        const size_t sidx = (size_t)t * BB + b;
        const ushort4 xq0 = *(const ushort4*)(xg + (((size_t)0 * NSAMP + sidx) * HIDN + hid) * LPP + l0);
        const ushort4 xq1 = *(const ushort4*)(xg + (((size_t)1 * NSAMP + sidx) * HIDN + hid) * LPP + l0);
        const ushort4 xq2 = *(const ushort4*)(xg + (((size_t)2 * NSAMP + sidx) * HIDN + hid) * LPP + l0);
        const ushort4 xq3 = *(const ushort4*)(xg + (((size_t)3 * NSAMP + sidx) * HIDN + hid) * LPP + l0);

        float acc[4][4];
        #pragma unroll
        for (int g = 0; g < 4; g++){
            #pragma unroll
            for (int j = 0; j < 4; j++) acc[g][j] = 0.f;
        }

        if (t > 0){
            // wait for all blocks to have written h(t-1)
            if (tid == 0){
                while (__hip_atomic_load(&cnt[t - 1], __ATOMIC_ACQUIRE,
                                         __HIP_MEMORY_SCOPE_AGENT) < 1024u){
                    __builtin_amdgcn_s_sleep(2);
                }
            }
            __syncthreads();

            const float* hb = out + (size_t)(t - 1) * (BB * HIDN * LPP)
                                  + (size_t)b * (HIDN * LPP);
            // 2-deep row prefetch: rows c (a) and c+1 (b2) live
            float4 ma = *(const float4*)(hb + l0);
            float ea0 = (l0 > 0)       ? hb[l0 - 1] : 0.f;
            float ea5 = (l0 + 4 < LPP) ? hb[l0 + 4] : 0.f;
            const float* h1 = hb + LPP;
            float4 mb = *(const float4*)(h1 + l0);
            float eb0 = (l0 > 0)       ? h1[l0 - 1] : 0.f;
            float eb5 = (l0 + 4 < LPP) ? h1[l0 + 4] : 0.f;

            for (int c = 0; c < HIDN; c += 2){
                // prefetch row c+2
                const float* h2 = hb + (size_t)((c + 2 < HIDN) ? c + 2 : HIDN - 1) * LPP;
                float4 mc = *(const float4*)(h2 + l0);
                float ec0 = (l0 > 0)       ? h2[l0 - 1] : 0.f;
                float ec5 = (l0 + 4 < LPP) ? h2[l0 + 4] : 0.f;

                // row c FMAs
                {
                    float win[6];
                    win[0] = ea0; win[1] = ma.x; win[2] = ma.y;
                    win[3] = ma.z; win[4] = ma.w; win[5] = ea5;
                    #pragma unroll
                    for (int k = 0; k < 3; ++k){
                        const float4 w = wl4[(c * 3 + k) * 4 + hp];
                        #pragma unroll
                        for (int j = 0; j < 4; ++j){
                            const float hk = win[j + k];
                            acc[0][j] += w.x * hk;
                            acc[1][j] += w.y * hk;
                            acc[2][j] += w.z * hk;
                            acc[3][j] += w.w * hk;
                        }
                    }
                }

                // prefetch row c+3
                const float* h3 = hb + (size_t)((c + 3 < HIDN) ? c + 3 : HIDN - 1) * LPP;
                float4 md = *(const float4*)(h3 + l0);
                float ed0 = (l0 > 0)       ? h3[l0 - 1] : 0.f;
                float ed5 = (l0 + 4 < LPP) ? h3[l0 + 4] : 0.f;

                // row c+1 FMAs
                {
                    float win[6];
                    win[0] = eb0; win[1] = mb.x; win[2] = mb.y;
                    win[3] = mb.z; win[4] = mb.w; win[5] = eb5;
                    #pragma unroll
                    for (int k = 0; k < 3; ++k){
                        const float4 w = wl4[((c + 1) * 3 + k) * 4 + hp];
                        #pragma unroll
                        for (int j = 0; j < 4; ++j){
                            const float hk = win[j + k];
                            acc[0][j] += w.x * hk;
                            acc[1][j] += w.y * hk;
                            acc[2][j] += w.z * hk;
                            acc[3][j] += w.w * hk;
                        }
                    }
                }

                ma = mc; ea0 = ec0; ea5 = ec5;
                mb = md; eb0 = ed0; eb5 = ed5;
            }
        }

        // epilogue: gates + state update + h write
        float pre[4][4];
        {
            pre[0][0] = acc[0][0] + bias0 + bf2f(xq0.x);
            pre[0][1] = acc[0][1] + bias0 + bf2f(xq0.y);
            pre[0][2] = acc[0][2] + bias0 + bf2f(xq0.z);
            pre[0][3] = acc[0][3] + bias0 + bf2f(xq0.w);
            pre[1][0] = acc[1][0] + bias1 + bf2f(xq1.x);
            pre[1][1] = acc[1][1] + bias1 + bf2f(xq1.y);
            pre[1][2] = acc[1][2] + bias1 + bf2f(xq1.z);
            pre[1][3] = acc[1][3] + bias1 + bf2f(xq1.w);
            pre[2][0] = acc[2][0] + bias2 + bf2f(xq2.x);
            pre[2][1] = acc[2][1] + bias2 + bf2f(xq2.y);
            pre[2][2] = acc[2][2] + bias2 + bf2f(xq2.z);
            pre[2][3] = acc[2][3] + bias2 + bf2f(xq2.w);
            pre[3][0] = acc[3][0] + bias3 + bf2f(xq3.x);
            pre[3][1] = acc[3][1] + bias3 + bf2f(xq3.y);
            pre[3][2] = acc[3][2] + bias3 + bf2f(xq3.z);
            pre[3][3] = acc[3][3] + bias3 + bf2f(xq3.w);
        }
        float4 hn;
        {
            const float ig = sigmoidf_(pre[0][0]);
            const float fg = sigmoidf_(pre[1][0]);
            const float gg = tanhf_(pre[2][0]);
            const float og = sigmoidf_(pre[3][0]);
            cv.x = fg * cv.x + ig * gg; hn.x = og * tanhf_(cv.x);
        }
        {
            const float ig = sigmoidf_(pre[0][1]);
            const float fg = sigmoidf_(pre[1][1]);
            const float gg = tanhf_(pre[2][1]);
            const float og = sigmoidf_(pre[3][1]);
            cv.y = fg * cv.y + ig * gg; hn.y = og * tanhf_(cv.y);
        }
        {
            const float ig = sigmoidf_(pre[0][2]);
            const float fg = sigmoidf_(pre[1][2]);
            const float gg = tanhf_(pre[2][2]);
            const float og = sigmoidf_(pre[3][2]);
            cv.z = fg * cv.z + ig * gg; hn.z = og * tanhf_(cv.z);
        }
        {
            const float ig = sigmoidf_(pre[0][3]);
            const float fg = sigmoidf_(pre[1][3]);
            const float gg = tanhf_(pre[2][3]);
            const float og = sigmoidf_(pre[3][3]);
            cv.w = fg * cv.w + ig * gg; hn.w = og * tanhf_(cv.w);
        }
        *(float4*)(out + (size_t)t * (BB * HIDN * LPP)
                       + ((size_t)b * HIDN + hid) * LPP + l0) = hn;

        // arrive: release h(t) device-wide
        if (t + 1 < TT){
            __threadfence();
            __syncthreads();
            if (tid == 0){
                __hip_atomic_fetch_add(&cnt[t], 1u, __ATOMIC_RELEASE,
                                       __HIP_MEMORY_SCOPE_AGENT);
            }
        }
    }
}

// =====================================================================
// Host side
// =====================================================================
extern "C" void kernel_launch(void* const* d_in, const int* in_sizes, int n_in,
                              void* d_out, int out_size, void* d_ws, size_t ws_size,
                              hipStream_t stream)
{
    const float* x = (const float*)d_in[0];

    const float* wxp[4] = {nullptr,nullptr,nullptr,nullptr};
    const float* bxp[4] = {nullptr,nullptr,nullptr,nullptr};
    const float* whp[4] = {nullptr,nullptr,nullptr,nullptr};
    const float* bhp[4] = {nullptr,nullptr,nullptr,nullptr};
    const float* lnw = nullptr; const float* lnb = nullptr;
    int nwx = 0, nwh = 0, pend = -1;
    for (int i = 1; i < n_in; i++){
        const float* p = (const float*)d_in[i];
        const int sz = in_sizes[i];
        if (sz == HIDN * CINC * 3)      { wxp[nwx] = p; pend = 0; }
        else if (sz == HIDN * HIDN * 3) { whp[nwh] = p; pend = 1; }
        else if (sz == HIDN)            { if (pend == 0) bxp[nwx++] = p; else bhp[nwh++] = p; pend = -1; }
        else if (sz == HIDN * LL)       { if (!lnw) lnw = p; else lnb = p; }
    }

    // Workspace: xg (bf16, 256 MiB), wT2 (768 KiB), counters (256 B).
    unsigned int*   xg_u32 = (unsigned int*)d_ws;
    unsigned short* xg_u16 = (unsigned short*)d_ws;
    const size_t xg_bytes = (size_t)4 * NSAMP * HIDN * LPP * 2;
    float* wT2 = (float*)((char*)d_ws + xg_bytes);
    unsigned int* cnt = (unsigned int*)((char*)d_ws + xg_bytes + (size_t)32 * 6144 * 4);
    float* out = (float*)d_out;

    hipMemsetAsync(cnt, 0, TT * sizeof(unsigned int), stream);

    phase1_kernel<<<dim3(NSAMP, 4), 512, 0, stream>>>(
        x, wxp[0], bxp[0], wxp[1], bxp[1], wxp[2], bxp[2], wxp[3], bxp[3],
        lnw, lnb, xg_u32);

    transpose_wh_kernel<<<dim3(32), 256, 0, stream>>>(
        whp[0], whp[1], whp[2], whp[3], wT2);

    phase2_persist<<<dim3(1024), 128, 0, stream>>>(
        xg_u16, wT2, bhp[0], bhp[1], bhp[2], bhp[3], out, cnt);
}